// Round 7
// baseline (831.485 us; speedup 1.0000x reference)
//
#include <hip/hip_runtime.h>
#include <hip/hip_cooperative_groups.h>
#include <math.h>

namespace cg = cooperative_groups;

#define HN       250
#define WN       400
#define N_RAYS   (HN * WN)        // 100000
#define N_SAMP   1000000
#define P_TENSO  50000
#define STEP_SZ  0.005f
#define DENS_SCALE 1.0f           // min(1/(1-0), 25) = 1
#define NB_SCAN  ((P_TENSO + 1023) / 1024)   // 49

// ---------------- workspace layout (bytes) ----------------
#define OFF_SDATA   0            // 1M x 32B reordered sample structs
#define OFF_RESULTS 32000000     // 1M x 16B per-sample (lt, r, g, b)
#define OFF_COUNTS  48000000     // 50K int
#define OFF_STARTS  48200000     // 50K int
#define OFF_CURSOR  48400000     // 50K int
#define OFF_BSUMS   48600000     // 256 int
#define OFF_RSTART  48601024     // (N_RAYS+1) int
#define WS_NEED     (48601024 + 400004 + 64)

// gather slab layout (floats), per wave
#define ROW_STRIDE 20                 // 16 ch + 4 pad
#define TV_F   (24 * ROW_STRIDE)      // 480
#define SLAB_F (TV_F + 16 + 48)       // 544

#define MEGA_BLOCKS_MAX 1024

// ---------------------------------------------------------------------------
// ONE cooperative kernel. All phases grid-stride -> correct for any grid size
// >= 64 blocks (P2a needs NB_SCAN=49 blocks).
// ---------------------------------------------------------------------------
__global__ __launch_bounds__(256, 4) void mega_kernel(
    const float* __restrict__ trivecs,   // (P,16,3,8)
    const float* __restrict__ densities, // (P,16)
    const float* __restrict__ colors,    // (P,16,3)
    const float* __restrict__ gws,       // (N,3)
    const float* __restrict__ gwl,       // (N,3)
    const float* __restrict__ t_min,     // (N_RAYS)
    const float* __restrict__ bg,        // (3)
    const int*   __restrict__ gis,       // (N,3)
    const int*   __restrict__ gil,       // (N,3)
    const int*   __restrict__ tenso_id,  // (N)
    const int*   __restrict__ ray_id,    // (N), sorted
    const int*   __restrict__ step_id,   // (N)
    float* __restrict__ out,             // [5*N_RAYS]
    float4* __restrict__ sdata,
    float4* __restrict__ results,
    int* __restrict__ counts,
    int* __restrict__ starts,
    int* __restrict__ cursor,
    int* __restrict__ bsums,
    int* __restrict__ ray_start)
{
    cg::grid_group grid = cg::this_grid();
    const int tix = blockIdx.x * 256 + threadIdx.x;
    const int gsz = gridDim.x * 256;
    __shared__ __align__(16) float smem[4 * SLAB_F];

    // ---- P0: zero tid counts ----
    for (int i = tix; i < P_TENSO; i += gsz) counts[i] = 0;
    grid.sync();

    // ---- P1: tid histogram + ray segment boundaries ----
    for (int n = tix; n < N_SAMP; n += gsz) {
        atomicAdd(&counts[tenso_id[n]], 1);
        int r = ray_id[n];
        int rprev = (n == 0) ? -1 : ray_id[n - 1];
        for (int q = rprev + 1; q <= r; ++q) ray_start[q] = n;
        if (n == N_SAMP - 1) {
            for (int q = r + 1; q <= N_RAYS; ++q) ray_start[q] = N_SAMP;
        }
    }
    grid.sync();

    // ---- P2a: block-local exclusive scan of counts (1024/block) ----
    {
        int* ilds = (int*)smem;
        const int b = blockIdx.x;
        if (b < NB_SCAN) {
            const int t = threadIdx.x;
            const int base = b * 1024;
            int v[4]; int s = 0;
            #pragma unroll
            for (int i = 0; i < 4; ++i) {
                int idx = base + t * 4 + i;
                v[i] = (idx < P_TENSO) ? counts[idx] : 0;
                s += v[i];
            }
            ilds[t] = s;
            __syncthreads();
            for (int d = 1; d < 256; d <<= 1) {
                int x = (t >= d) ? ilds[t - d] : 0;
                __syncthreads();
                ilds[t] += x;
                __syncthreads();
            }
            int run = (t > 0) ? ilds[t - 1] : 0;
            #pragma unroll
            for (int i = 0; i < 4; ++i) {
                int idx = base + t * 4 + i;
                if (idx < P_TENSO) starts[idx] = run;
                run += v[i];
            }
            if (t == 255) bsums[b] = ilds[255];
        }
    }
    grid.sync();

    // ---- P2b: every block redundantly scans the 49 block sums, then adds ----
    {
        int* bscan = (int*)smem;
        if (threadIdx.x < 64) {
            int t = threadIdx.x;
            int v = (t < NB_SCAN) ? bsums[t] : 0;
            int incl = v;
            #pragma unroll
            for (int d = 1; d < 64; d <<= 1) {
                int u = __shfl_up(incl, d, 64);
                if (t >= d) incl += u;
            }
            if (t < NB_SCAN) bscan[t] = incl - v;   // exclusive
        }
        __syncthreads();
        for (int i = tix; i < P_TENSO; i += gsz) {
            int v = starts[i] + bscan[i >> 10];
            starts[i] = v;
            cursor[i] = v;
        }
    }
    grid.sync();

    // ---- P3: scatter samples into tid-grouped order (32B structs) ----
    for (int n = tix; n < N_SAMP; n += gsz) {
        int tid = tenso_id[n];
        int pos = atomicAdd(&cursor[tid], 1);
        unsigned bits = (unsigned)gis[n*3+0] | ((unsigned)gis[n*3+1] << 3) | ((unsigned)gis[n*3+2] << 6)
                      | ((unsigned)gil[n*3+0] << 9) | ((unsigned)gil[n*3+1] << 12) | ((unsigned)gil[n*3+2] << 15);
        float4 A = make_float4(gws[n*3+0], gws[n*3+1], gws[n*3+2], gwl[n*3+0]);
        float4 B = make_float4(gwl[n*3+1], gwl[n*3+2], __uint_as_float(bits), __uint_as_float((unsigned)n));
        sdata[(size_t)pos * 2 + 0] = A;
        sdata[(size_t)pos * 2 + 1] = B;
    }
    grid.sync();

    // ---- P4: gather — wave per tid (grid-stride); slab staged in LDS ----
    {
        float* results_f = (float*)results;
        const int lane = threadIdx.x & 63;
        const int wv   = threadIdx.x >> 6;
        const int gwave  = blockIdx.x * 4 + wv;
        const int nwaves = gridDim.x * 4;
        float* slab = smem + wv * SLAB_F;
        float* dl   = slab + TV_F;          // 16 densities
        float* cl   = dl + 16;              // colors (3,16)
        const int g = lane >> 2;            // sample slot 0..15
        const int j = lane & 3;             // channel group

        for (int t = gwave; t < P_TENSO; t += nwaves) {
            const int start = starts[t];
            const int cnt   = counts[t];
            if (cnt == 0) continue;

            // stage slab: input l = c*24 + (a*8+d) -> slab[(a*8+d)*20 + c]
            const float* tvg = trivecs + (size_t)t * 384;
            #pragma unroll
            for (int i = 0; i < 6; ++i) {
                int l = lane + i * 64;
                int c = l / 24;
                int rem = l - c * 24;
                slab[rem * ROW_STRIDE + c] = tvg[l];
            }
            if (lane < 16) dl[lane] = densities[(size_t)t * 16 + lane];
            if (lane < 48) {
                int c = lane / 3, k = lane - c * 3;
                cl[k * 16 + c] = colors[(size_t)t * 48 + lane];
            }
            // same-wave LDS RAW: compiler inserts lgkmcnt waits

            const float4 dens4 = *(const float4*)(dl + 4 * j);
            const float4 col0  = *(const float4*)(cl + 4 * j);
            const float4 col1  = *(const float4*)(cl + 16 + 4 * j);
            const float4 col2  = *(const float4*)(cl + 32 + 4 * j);

            const int end = start + cnt;
            const int niter = (cnt + 15) >> 4;

            for (int it = 0; it < niter; ++it) {
                const int pos = start + it * 16 + g;
                const bool valid = (pos < end);
                const int cp = valid ? pos : (end - 1);
                const float4 A = sdata[(size_t)cp * 2 + 0];
                const float4 B = sdata[(size_t)cp * 2 + 1];
                const unsigned bits = __float_as_uint(B.z);
                const unsigned orig = __float_as_uint(B.w);

                float4 f;
                {
                    const int is = bits & 7, il = (bits >> 9) & 7;
                    const float4 vs = *(const float4*)(slab + is * ROW_STRIDE + 4 * j);
                    const float4 vl = *(const float4*)(slab + il * ROW_STRIDE + 4 * j);
                    f.x = vs.x * A.x + vl.x * A.w;
                    f.y = vs.y * A.x + vl.y * A.w;
                    f.z = vs.z * A.x + vl.z * A.w;
                    f.w = vs.w * A.x + vl.w * A.w;
                }
                {
                    const int is = (bits >> 3) & 7, il = (bits >> 12) & 7;
                    const float4 vs = *(const float4*)(slab + (8 + is) * ROW_STRIDE + 4 * j);
                    const float4 vl = *(const float4*)(slab + (8 + il) * ROW_STRIDE + 4 * j);
                    f.x *= vs.x * A.y + vl.x * B.x;
                    f.y *= vs.y * A.y + vl.y * B.x;
                    f.z *= vs.z * A.y + vl.z * B.x;
                    f.w *= vs.w * A.y + vl.w * B.x;
                }
                {
                    const int is = (bits >> 6) & 7, il = (bits >> 15) & 7;
                    const float4 vs = *(const float4*)(slab + (16 + is) * ROW_STRIDE + 4 * j);
                    const float4 vl = *(const float4*)(slab + (16 + il) * ROW_STRIDE + 4 * j);
                    f.x *= vs.x * A.z + vl.x * B.y;
                    f.y *= vs.y * A.z + vl.y * B.y;
                    f.z *= vs.z * A.z + vl.z * B.y;
                    f.w *= vs.w * A.z + vl.w * B.y;
                }

                float s0 = f.x * dens4.x + f.y * dens4.y + f.z * dens4.z + f.w * dens4.w;
                float s1 = f.x * col0.x  + f.y * col0.y  + f.z * col0.z  + f.w * col0.w;
                float s2 = f.x * col1.x  + f.y * col1.y  + f.z * col1.z  + f.w * col1.w;
                float s3 = f.x * col2.x  + f.y * col2.y  + f.z * col2.z  + f.w * col2.w;

                s0 += __shfl_xor(s0, 1); s0 += __shfl_xor(s0, 2);
                s1 += __shfl_xor(s1, 1); s1 += __shfl_xor(s1, 2);
                s2 += __shfl_xor(s2, 1); s2 += __shfl_xor(s2, 2);
                s3 += __shfl_xor(s3, 1); s3 += __shfl_xor(s3, 2);

                const float sj = (j == 0) ? s0 : (j == 1) ? s1 : (j == 2) ? s2 : s3;
                float val;
                if (j == 0) {
                    float dens = fmaxf(sj, 0.0f) + __logf(1.0f + __expf(-fabsf(sj)));
                    val = -(dens * DENS_SCALE) * STEP_SZ;        // lt
                } else {
                    val = 1.0f / (1.0f + __expf(-sj));           // sigmoid
                }
                if (valid) results_f[(size_t)orig * 4 + j] = val;
            }
        }
    }
    grid.sync();

    // ---- P5: per-ray sequential transmittance + accumulate ----
    for (int r = tix; r < N_RAYS; r += gsz) {
        const int s = ray_start[r];
        const int e = ray_start[r + 1];
        const float tmin_r = t_min[r];

        float T = 0.0f, aR = 0.0f, aG = 0.0f, aB = 0.0f, aD = 0.0f;
        for (int n = s; n < e; ++n) {
            float4 res = results[n];
            const float lt = res.x;
            const float w = (1.0f - __expf(lt)) * __expf(T);
            T += lt;
            const float z = tmin_r + (float)step_id[n] * STEP_SZ;
            aR += w * res.y;
            aG += w * res.z;
            aB += w * res.w;
            aD += w * z;
        }
        const float bgw = __expf(T);
        out[0 * N_RAYS + r] = aR + bgw * bg[0];
        out[1 * N_RAYS + r] = aG + bgw * bg[1];
        out[2 * N_RAYS + r] = aB + bgw * bg[2];
        out[3 * N_RAYS + r] = aD;
        out[4 * N_RAYS + r] = 1.0f - bgw;
    }
}

// ===========================================================================
// R5 multi-kernel pipeline (fallback when cooperative launch is refused).
// ===========================================================================
__global__ __launch_bounds__(256) void zero_ints(int* p, int n) {
    int i = blockIdx.x * 256 + threadIdx.x;
    if (i < n) p[i] = 0;
}

__global__ __launch_bounds__(256) void hist_and_bounds(
    const int* __restrict__ tenso_id, const int* __restrict__ ray_id,
    int* __restrict__ counts, int* __restrict__ ray_start) {
    int n = blockIdx.x * 256 + threadIdx.x;
    if (n >= N_SAMP) return;
    atomicAdd(&counts[tenso_id[n]], 1);
    int r = ray_id[n];
    int rprev = (n == 0) ? -1 : ray_id[n - 1];
    for (int q = rprev + 1; q <= r; ++q) ray_start[q] = n;
    if (n == N_SAMP - 1) {
        for (int q = r + 1; q <= N_RAYS; ++q) ray_start[q] = N_SAMP;
    }
}

__global__ __launch_bounds__(256) void scan_local(const int* __restrict__ in,
                                                  int* __restrict__ out,
                                                  int* __restrict__ bsums, int n) {
    __shared__ int lds[256];
    const int t = threadIdx.x;
    const int base = blockIdx.x * 1024;
    int v[4]; int s = 0;
    #pragma unroll
    for (int i = 0; i < 4; ++i) {
        int idx = base + t * 4 + i;
        v[i] = (idx < n) ? in[idx] : 0;
        s += v[i];
    }
    lds[t] = s;
    __syncthreads();
    for (int d = 1; d < 256; d <<= 1) {
        int x = (t >= d) ? lds[t - d] : 0;
        __syncthreads();
        lds[t] += x;
        __syncthreads();
    }
    int run = (t > 0) ? lds[t - 1] : 0;
    #pragma unroll
    for (int i = 0; i < 4; ++i) {
        int idx = base + t * 4 + i;
        if (idx < n) out[idx] = run;
        run += v[i];
    }
    if (t == 255) bsums[blockIdx.x] = lds[255];
}

__global__ __launch_bounds__(64) void scan_totals(int* __restrict__ bsums, int nb) {
    int t = threadIdx.x;
    int v = (t < nb) ? bsums[t] : 0;
    #pragma unroll
    for (int d = 1; d < 64; d <<= 1) {
        int u = __shfl_up(v, d, 64);
        if (t >= d) v += u;
    }
    int excl = __shfl_up(v, 1, 64);
    if (t == 0) excl = 0;
    if (t < nb) bsums[t] = excl;
}

__global__ __launch_bounds__(256) void scan_add(int* __restrict__ starts,
                                                int* __restrict__ cursor,
                                                const int* __restrict__ bsums, int n) {
    int i = blockIdx.x * 256 + threadIdx.x;
    if (i < n) { int v = starts[i] + bsums[i >> 10]; starts[i] = v; cursor[i] = v; }
}

__global__ __launch_bounds__(256) void scatter_samples(
    const int*   __restrict__ tenso_id,
    const int*   __restrict__ gis, const int* __restrict__ gil,
    const float* __restrict__ gws, const float* __restrict__ gwl,
    int* __restrict__ cursor,
    float4* __restrict__ sdata)
{
    int n = blockIdx.x * 256 + threadIdx.x;
    if (n >= N_SAMP) return;
    int tid = tenso_id[n];
    int pos = atomicAdd(&cursor[tid], 1);
    unsigned bits = (unsigned)gis[n*3+0] | ((unsigned)gis[n*3+1] << 3) | ((unsigned)gis[n*3+2] << 6)
                  | ((unsigned)gil[n*3+0] << 9) | ((unsigned)gil[n*3+1] << 12) | ((unsigned)gil[n*3+2] << 15);
    float4 A = make_float4(gws[n*3+0], gws[n*3+1], gws[n*3+2], gwl[n*3+0]);
    float4 B = make_float4(gwl[n*3+1], gwl[n*3+2], __uint_as_float(bits), __uint_as_float((unsigned)n));
    sdata[(size_t)pos * 2 + 0] = A;
    sdata[(size_t)pos * 2 + 1] = B;
}

__global__ __launch_bounds__(256) void gather_phase(
    const float* __restrict__ trivecs,
    const float* __restrict__ densities,
    const float* __restrict__ colors,
    const int*   __restrict__ starts,
    const int*   __restrict__ counts,
    const float4* __restrict__ sdata,
    float* __restrict__ results_f)
{
    __shared__ __align__(16) float lds[4 * SLAB_F];
    const int lane = threadIdx.x & 63;
    const int wv   = threadIdx.x >> 6;
    const int t    = blockIdx.x * 4 + wv;
    if (t >= P_TENSO) return;

    const int start = starts[t];
    const int cnt   = counts[t];
    if (cnt == 0) return;

    float* slab = lds + wv * SLAB_F;
    float* dl   = slab + TV_F;
    float* cl   = dl + 16;

    const float* tvg = trivecs + (size_t)t * 384;
    #pragma unroll
    for (int i = 0; i < 6; ++i) {
        int l = lane + i * 64;
        int c = l / 24;
        int rem = l - c * 24;
        slab[rem * ROW_STRIDE + c] = tvg[l];
    }
    if (lane < 16) dl[lane] = densities[(size_t)t * 16 + lane];
    if (lane < 48) {
        int c = lane / 3, k = lane - c * 3;
        cl[k * 16 + c] = colors[(size_t)t * 48 + lane];
    }

    const int g = lane >> 2;
    const int j = lane & 3;

    const float4 dens4 = *(const float4*)(dl + 4 * j);
    const float4 col0  = *(const float4*)(cl + 4 * j);
    const float4 col1  = *(const float4*)(cl + 16 + 4 * j);
    const float4 col2  = *(const float4*)(cl + 32 + 4 * j);

    const int end = start + cnt;
    const int niter = (cnt + 15) >> 4;

    for (int it = 0; it < niter; ++it) {
        const int pos = start + it * 16 + g;
        const bool valid = (pos < end);
        const int cp = valid ? pos : (end - 1);
        const float4 A = sdata[(size_t)cp * 2 + 0];
        const float4 B = sdata[(size_t)cp * 2 + 1];
        const unsigned bits = __float_as_uint(B.z);
        const unsigned orig = __float_as_uint(B.w);

        float4 f;
        {
            const int is = bits & 7, il = (bits >> 9) & 7;
            const float4 vs = *(const float4*)(slab + is * ROW_STRIDE + 4 * j);
            const float4 vl = *(const float4*)(slab + il * ROW_STRIDE + 4 * j);
            f.x = vs.x * A.x + vl.x * A.w;
            f.y = vs.y * A.x + vl.y * A.w;
            f.z = vs.z * A.x + vl.z * A.w;
            f.w = vs.w * A.x + vl.w * A.w;
        }
        {
            const int is = (bits >> 3) & 7, il = (bits >> 12) & 7;
            const float4 vs = *(const float4*)(slab + (8 + is) * ROW_STRIDE + 4 * j);
            const float4 vl = *(const float4*)(slab + (8 + il) * ROW_STRIDE + 4 * j);
            f.x *= vs.x * A.y + vl.x * B.x;
            f.y *= vs.y * A.y + vl.y * B.x;
            f.z *= vs.z * A.y + vl.z * B.x;
            f.w *= vs.w * A.y + vl.w * B.x;
        }
        {
            const int is = (bits >> 6) & 7, il = (bits >> 15) & 7;
            const float4 vs = *(const float4*)(slab + (16 + is) * ROW_STRIDE + 4 * j);
            const float4 vl = *(const float4*)(slab + (16 + il) * ROW_STRIDE + 4 * j);
            f.x *= vs.x * A.z + vl.x * B.y;
            f.y *= vs.y * A.z + vl.y * B.y;
            f.z *= vs.z * A.z + vl.z * B.y;
            f.w *= vs.w * A.z + vl.w * B.y;
        }

        float s0 = f.x * dens4.x + f.y * dens4.y + f.z * dens4.z + f.w * dens4.w;
        float s1 = f.x * col0.x  + f.y * col0.y  + f.z * col0.z  + f.w * col0.w;
        float s2 = f.x * col1.x  + f.y * col1.y  + f.z * col1.z  + f.w * col1.w;
        float s3 = f.x * col2.x  + f.y * col2.y  + f.z * col2.z  + f.w * col2.w;

        s0 += __shfl_xor(s0, 1); s0 += __shfl_xor(s0, 2);
        s1 += __shfl_xor(s1, 1); s1 += __shfl_xor(s1, 2);
        s2 += __shfl_xor(s2, 1); s2 += __shfl_xor(s2, 2);
        s3 += __shfl_xor(s3, 1); s3 += __shfl_xor(s3, 2);

        const float sj = (j == 0) ? s0 : (j == 1) ? s1 : (j == 2) ? s2 : s3;
        float val;
        if (j == 0) {
            float dens = fmaxf(sj, 0.0f) + __logf(1.0f + __expf(-fabsf(sj)));
            val = -(dens * DENS_SCALE) * STEP_SZ;
        } else {
            val = 1.0f / (1.0f + __expf(-sj));
        }
        if (valid) results_f[(size_t)orig * 4 + j] = val;
    }
}

__global__ __launch_bounds__(256) void ray_render(
    const float4* __restrict__ results,
    const float*  __restrict__ t_min,
    const float*  __restrict__ bg,
    const int*    __restrict__ ray_start,
    const int*    __restrict__ step_id,
    float* __restrict__ out)
{
    int r = blockIdx.x * 256 + threadIdx.x;
    if (r >= N_RAYS) return;
    const int s = ray_start[r];
    const int e = ray_start[r + 1];
    const float tmin_r = t_min[r];

    float T = 0.0f, aR = 0.0f, aG = 0.0f, aB = 0.0f, aD = 0.0f;
    for (int n = s; n < e; ++n) {
        float4 res = results[n];
        const float lt = res.x;
        const float w = (1.0f - __expf(lt)) * __expf(T);
        T += lt;
        const float z = tmin_r + (float)step_id[n] * STEP_SZ;
        aR += w * res.y;
        aG += w * res.z;
        aB += w * res.w;
        aD += w * z;
    }
    const float bgw = __expf(T);
    out[0 * N_RAYS + r] = aR + bgw * bg[0];
    out[1 * N_RAYS + r] = aG + bgw * bg[1];
    out[2 * N_RAYS + r] = aB + bgw * bg[2];
    out[3 * N_RAYS + r] = aD;
    out[4 * N_RAYS + r] = 1.0f - bgw;
}

// ---------------------------------------------------------------------------
// Fallback (ws too small): single fused kernel, original layouts.
// ---------------------------------------------------------------------------
__global__ __launch_bounds__(256) void trivec_render_fallback(
    const float* __restrict__ trivecs, const float* __restrict__ densities,
    const float* __restrict__ colors, const float* __restrict__ gws,
    const float* __restrict__ gwl, const float* __restrict__ t_min,
    const float* __restrict__ bg, const int* __restrict__ gis,
    const int* __restrict__ gil, const int* __restrict__ tenso_id,
    const int* __restrict__ ray_id, const int* __restrict__ step_id,
    float* __restrict__ out)
{
    const int lane = threadIdx.x & 63;
    const int r = blockIdx.x * 4 + (threadIdx.x >> 6);
    if (r >= N_RAYS) return;
    const int c = lane & 15;
    const int g = lane >> 4;
    int lo = 0, hi = N_SAMP;
    while (lo < hi) { int mid = (lo + hi) >> 1; if (ray_id[mid] < r) lo = mid + 1; else hi = mid; }
    const int seg_start = lo;
    hi = N_SAMP;
    while (lo < hi) { int mid = (lo + hi) >> 1; if (ray_id[mid] < r + 1) lo = mid + 1; else hi = mid; }
    const int seg_end = lo;
    const float tmin_r = t_min[r];
    float Tlog = 0.0f, accR = 0.0f, accG = 0.0f, accB = 0.0f, accD = 0.0f;
    const int niter = (seg_end - seg_start + 3) >> 2;
    for (int it = 0; it < niter; ++it) {
        const int n = seg_start + it * 4 + g;
        const bool valid = (n < seg_end);
        const int nc = valid ? n : (seg_end - 1);
        const int tid = tenso_id[nc];
        const float* tv = trivecs + (size_t)tid * 384 + c * 24;
        float f = 1.0f;
        #pragma unroll
        for (int a = 0; a < 3; ++a) {
            const int is = gis[nc*3+a], il = gil[nc*3+a];
            const float wS = gws[nc*3+a], wL = gwl[nc*3+a];
            f *= (tv[a*8+is] * wS + tv[a*8+il] * wL);
        }
        const float dns = densities[(size_t)tid * 16 + c];
        const float* colp = colors + ((size_t)tid * 16 + c) * 3;
        float s0 = f*dns, s1 = f*colp[0], s2 = f*colp[1], s3 = f*colp[2];
        #pragma unroll
        for (int m = 1; m < 16; m <<= 1) {
            s0 += __shfl_xor(s0, m); s1 += __shfl_xor(s1, m);
            s2 += __shfl_xor(s2, m); s3 += __shfl_xor(s3, m);
        }
        float dens = fmaxf(s0, 0.0f) + __logf(1.0f + __expf(-fabsf(s0)));
        const float lt = valid ? (-dens * STEP_SZ) : 0.0f;
        const float alpha = 1.0f - __expf(lt);
        const float rr = 1.0f/(1.0f+__expf(-s1)), gg = 1.0f/(1.0f+__expf(-s2)), bb = 1.0f/(1.0f+__expf(-s3));
        const float z = tmin_r + (float)step_id[nc] * STEP_SZ;
        const float lt0 = __shfl(lt,0), lt1 = __shfl(lt,16), lt2 = __shfl(lt,32), lt3 = __shfl(lt,48);
        float excl = Tlog;
        if (g > 0) excl += lt0;
        if (g > 1) excl += lt1;
        if (g > 2) excl += lt2;
        const float w = alpha * __expf(excl);
        Tlog += lt0 + lt1 + lt2 + lt3;
        accR += w*rr; accG += w*gg; accB += w*bb; accD += w*z;
    }
    accR += __shfl_xor(accR,16); accR += __shfl_xor(accR,32);
    accG += __shfl_xor(accG,16); accG += __shfl_xor(accG,32);
    accB += __shfl_xor(accB,16); accB += __shfl_xor(accB,32);
    accD += __shfl_xor(accD,16); accD += __shfl_xor(accD,32);
    const float bgw = __expf(Tlog);
    if (lane == 0) {
        out[0*N_RAYS+r] = accR + bgw*bg[0];
        out[1*N_RAYS+r] = accG + bgw*bg[1];
        out[2*N_RAYS+r] = accB + bgw*bg[2];
        out[3*N_RAYS+r] = accD;
        out[4*N_RAYS+r] = 1.0f - bgw;
    }
}

extern "C" void kernel_launch(void* const* d_in, const int* in_sizes, int n_in,
                              void* d_out, int out_size, void* d_ws, size_t ws_size,
                              hipStream_t stream) {
    const float* trivecs   = (const float*)d_in[0];
    const float* densities = (const float*)d_in[1];
    const float* colors    = (const float*)d_in[2];
    const float* gws       = (const float*)d_in[3];
    const float* gwl       = (const float*)d_in[4];
    const float* t_min     = (const float*)d_in[5];
    const float* bg        = (const float*)d_in[6];
    const int*   gis       = (const int*)d_in[7];
    const int*   gil       = (const int*)d_in[8];
    const int*   tenso_id  = (const int*)d_in[9];
    const int*   ray_id    = (const int*)d_in[10];
    const int*   step_id   = (const int*)d_in[11];
    float* out = (float*)d_out;

    if (ws_size < (size_t)WS_NEED) {
        trivec_render_fallback<<<(N_RAYS + 3) / 4, 256, 0, stream>>>(
            trivecs, densities, colors, gws, gwl, t_min, bg,
            gis, gil, tenso_id, ray_id, step_id, out);
        return;
    }

    char* ws = (char*)d_ws;
    float4* sdata    = (float4*)(ws + OFF_SDATA);
    float4* results  = (float4*)(ws + OFF_RESULTS);
    int*    counts   = (int*)(ws + OFF_COUNTS);
    int*    starts   = (int*)(ws + OFF_STARTS);
    int*    cursor   = (int*)(ws + OFF_CURSOR);
    int*    bsums    = (int*)(ws + OFF_BSUMS);
    int*    raystart = (int*)(ws + OFF_RSTART);

    // ---- cooperative path: query real co-residency, clamp grid, check rc ----
    bool coop_ok = false;
    {
        int blocksPerCU = 0;
        hipError_t e1 = hipOccupancyMaxActiveBlocksPerMultiprocessor(
            &blocksPerCU, (const void*)mega_kernel, 256, 0);
        int nCU = 0;
        hipError_t e2 = hipDeviceGetAttribute(&nCU, hipDeviceAttributeMultiprocessorCount, 0);
        if (e1 == hipSuccess && e2 == hipSuccess && blocksPerCU > 0 && nCU > 0) {
            int blocks = blocksPerCU * nCU;
            if (blocks > MEGA_BLOCKS_MAX) blocks = MEGA_BLOCKS_MAX;
            if (blocks >= 64) {   // P2a needs >= NB_SCAN(49) blocks
                void* args[] = {
                    (void*)&trivecs, (void*)&densities, (void*)&colors,
                    (void*)&gws, (void*)&gwl, (void*)&t_min, (void*)&bg,
                    (void*)&gis, (void*)&gil, (void*)&tenso_id, (void*)&ray_id,
                    (void*)&step_id, (void*)&out,
                    (void*)&sdata, (void*)&results, (void*)&counts, (void*)&starts,
                    (void*)&cursor, (void*)&bsums, (void*)&raystart
                };
                hipError_t e3 = hipLaunchCooperativeKernel(
                    (void*)mega_kernel, dim3(blocks), dim3(256), args, 0, stream);
                coop_ok = (e3 == hipSuccess);
            }
        }
    }
    if (coop_ok) return;

    // ---- fallback: proven R5 multi-kernel pipeline ----
    const int NB = NB_SCAN;
    zero_ints<<<(P_TENSO + 255) / 256, 256, 0, stream>>>(counts, P_TENSO);
    hist_and_bounds<<<(N_SAMP + 255) / 256, 256, 0, stream>>>(tenso_id, ray_id, counts, raystart);
    scan_local<<<NB, 256, 0, stream>>>(counts, starts, bsums, P_TENSO);
    scan_totals<<<1, 64, 0, stream>>>(bsums, NB);
    scan_add<<<(P_TENSO + 255) / 256, 256, 0, stream>>>(starts, cursor, bsums, P_TENSO);
    scatter_samples<<<(N_SAMP + 255) / 256, 256, 0, stream>>>(
        tenso_id, gis, gil, gws, gwl, cursor, sdata);
    gather_phase<<<(P_TENSO + 3) / 4, 256, 0, stream>>>(
        trivecs, densities, colors, starts, counts, sdata, (float*)results);
    ray_render<<<(N_RAYS + 255) / 256, 256, 0, stream>>>(
        results, t_min, bg, raystart, step_id, out);
}

// Round 8
// 335.960 us; speedup vs baseline: 2.4750x; 2.4750x over previous
//
#include <hip/hip_runtime.h>
#include <math.h>

#define HN       250
#define WN       400
#define N_RAYS   (HN * WN)        // 100000
#define N_SAMP   1000000
#define P_TENSO  50000
#define STEP_SZ  0.005f
#define DENS_SCALE 1.0f           // min(1/(1-0), 25) = 1
#define NB_SCAN  ((P_TENSO + 1023) / 1024)   // 49

// NOTE (R7 post-mortem): cooperative mega-kernel measured grid.sync() at
// ~100 us per sync on MI355X (8 XCDs, device-scope fence + cross-XCD spin).
// Multi-kernel dispatch boundaries are far cheaper. Do not re-fuse.

// ---------------- workspace layout (bytes) ----------------
// pack    : 1M x 32B sample structs in ORIGINAL order (coalesced W)
// results : 1M x 16B (lt,r,g,b) in TID order (coalesced W)
// perm    : 1M int, pos -> n
// iperm   : 1M int, n -> pos
#define OFF_PACK    0
#define OFF_RESULTS 32000000
#define OFF_PERM    48000000
#define OFF_IPERM   52000000
#define OFF_COUNTS  56000000
#define OFF_STARTS  56200000
#define OFF_CURSOR  56400000
#define OFF_BSUMS   56600000
#define OFF_RSTART  56601024     // (N_RAYS+1) int
#define WS_NEED     (56601024 + 400004 + 64)

// gather slab layout (floats), per wave
#define ROW_STRIDE 20                 // 16 ch + 4 pad
#define TV_F   (24 * ROW_STRIDE)      // 480
#define SLAB_F (TV_F + 16 + 48)       // 544

__global__ __launch_bounds__(256) void zero_ints(int* p, int n) {
    int i = blockIdx.x * 256 + threadIdx.x;
    if (i < n) p[i] = 0;
}

// pack samples (coalesced W) + tid histogram + ray segment bounds, one pass
__global__ __launch_bounds__(256) void pack_hist_bounds(
    const int*   __restrict__ tenso_id,
    const int*   __restrict__ ray_id,     // sorted
    const int*   __restrict__ gis, const int* __restrict__ gil,
    const float* __restrict__ gws, const float* __restrict__ gwl,
    int* __restrict__ counts,
    int* __restrict__ ray_start,
    float4* __restrict__ pack)
{
    int n = blockIdx.x * 256 + threadIdx.x;
    if (n >= N_SAMP) return;

    atomicAdd(&counts[tenso_id[n]], 1);

    unsigned bits = (unsigned)gis[n*3+0] | ((unsigned)gis[n*3+1] << 3) | ((unsigned)gis[n*3+2] << 6)
                  | ((unsigned)gil[n*3+0] << 9) | ((unsigned)gil[n*3+1] << 12) | ((unsigned)gil[n*3+2] << 15);
    float4 A = make_float4(gws[n*3+0], gws[n*3+1], gws[n*3+2], gwl[n*3+0]);
    float4 B = make_float4(gwl[n*3+1], gwl[n*3+2], __uint_as_float(bits), 0.0f);
    pack[(size_t)n * 2 + 0] = A;
    pack[(size_t)n * 2 + 1] = B;

    int r = ray_id[n];
    int rprev = (n == 0) ? -1 : ray_id[n - 1];
    for (int q = rprev + 1; q <= r; ++q) ray_start[q] = n;
    if (n == N_SAMP - 1) {
        for (int q = r + 1; q <= N_RAYS; ++q) ray_start[q] = N_SAMP;
    }
}

// block scans 1024 elements (4/thread), writes exclusive scan + block total
__global__ __launch_bounds__(256) void scan_local(const int* __restrict__ in,
                                                  int* __restrict__ out,
                                                  int* __restrict__ bsums, int n) {
    __shared__ int lds[256];
    const int t = threadIdx.x;
    const int base = blockIdx.x * 1024;
    int v[4]; int s = 0;
    #pragma unroll
    for (int i = 0; i < 4; ++i) {
        int idx = base + t * 4 + i;
        v[i] = (idx < n) ? in[idx] : 0;
        s += v[i];
    }
    lds[t] = s;
    __syncthreads();
    for (int d = 1; d < 256; d <<= 1) {
        int x = (t >= d) ? lds[t - d] : 0;
        __syncthreads();
        lds[t] += x;
        __syncthreads();
    }
    int run = (t > 0) ? lds[t - 1] : 0;
    #pragma unroll
    for (int i = 0; i < 4; ++i) {
        int idx = base + t * 4 + i;
        if (idx < n) out[idx] = run;
        run += v[i];
    }
    if (t == 255) bsums[blockIdx.x] = lds[255];
}

__global__ __launch_bounds__(64) void scan_totals(int* __restrict__ bsums, int nb) {
    int t = threadIdx.x;
    int v = (t < nb) ? bsums[t] : 0;
    #pragma unroll
    for (int d = 1; d < 64; d <<= 1) {
        int u = __shfl_up(v, d, 64);
        if (t >= d) v += u;
    }
    int excl = __shfl_up(v, 1, 64);
    if (t == 0) excl = 0;
    if (t < nb) bsums[t] = excl;
}

__global__ __launch_bounds__(256) void scan_add(int* __restrict__ starts,
                                                int* __restrict__ cursor,
                                                const int* __restrict__ bsums, int n) {
    int i = blockIdx.x * 256 + threadIdx.x;
    if (i < n) { int v = starts[i] + bsums[i >> 10]; starts[i] = v; cursor[i] = v; }
}

// permutation only: perm[pos]=n (4B random, L2-absorbed), iperm[n]=pos (coalesced)
__global__ __launch_bounds__(256) void scatter_perm(
    const int* __restrict__ tenso_id,
    int* __restrict__ cursor,
    int* __restrict__ perm,
    int* __restrict__ iperm)
{
    int n = blockIdx.x * 256 + threadIdx.x;
    if (n >= N_SAMP) return;
    int tid = tenso_id[n];
    int pos = atomicAdd(&cursor[tid], 1);
    perm[pos] = n;
    iperm[n] = pos;
}

// ---------------------------------------------------------------------------
// Gather: one wave per tensoRF id; lanes = 16 samples x 4 channel-groups.
// Reads perm coalesced, pack[n] random 32B (quad-broadcast, L2/L3-served).
// Writes results[pos] COALESCED (256B per wave).
// ---------------------------------------------------------------------------
__global__ __launch_bounds__(256) void gather_phase(
    const float* __restrict__ trivecs,   // (P,16,3,8)
    const float* __restrict__ densities, // (P,16)
    const float* __restrict__ colors,    // (P,16,3)
    const int*   __restrict__ starts,
    const int*   __restrict__ counts,
    const int*   __restrict__ perm,
    const float4* __restrict__ pack,
    float* __restrict__ results_f)       // [pos*4 + j]
{
    __shared__ __align__(16) float lds[4 * SLAB_F];
    const int lane = threadIdx.x & 63;
    const int wv   = threadIdx.x >> 6;
    const int t    = blockIdx.x * 4 + wv;
    if (t >= P_TENSO) return;

    const int start = starts[t];
    const int cnt   = counts[t];
    if (cnt == 0) return;

    float* slab = lds + wv * SLAB_F;
    float* dl   = slab + TV_F;
    float* cl   = dl + 16;

    // stage slab: input l = c*24 + (a*8+d) -> slab[(a*8+d)*20 + c]
    const float* tvg = trivecs + (size_t)t * 384;
    #pragma unroll
    for (int i = 0; i < 6; ++i) {
        int l = lane + i * 64;
        int c = l / 24;
        int rem = l - c * 24;
        slab[rem * ROW_STRIDE + c] = tvg[l];
    }
    if (lane < 16) dl[lane] = densities[(size_t)t * 16 + lane];
    if (lane < 48) {
        int c = lane / 3, k = lane - c * 3;
        cl[k * 16 + c] = colors[(size_t)t * 48 + lane];
    }

    const int g = lane >> 2;   // sample slot 0..15
    const int j = lane & 3;    // channel group

    const float4 dens4 = *(const float4*)(dl + 4 * j);
    const float4 col0  = *(const float4*)(cl + 4 * j);
    const float4 col1  = *(const float4*)(cl + 16 + 4 * j);
    const float4 col2  = *(const float4*)(cl + 32 + 4 * j);

    const int end = start + cnt;
    const int niter = (cnt + 15) >> 4;

    for (int it = 0; it < niter; ++it) {
        const int pos = start + it * 16 + g;
        const bool valid = (pos < end);
        const int cp = valid ? pos : (end - 1);
        const int n = perm[cp];                       // coalesced
        const float4 A = pack[(size_t)n * 2 + 0];     // random 32B, quad-broadcast
        const float4 B = pack[(size_t)n * 2 + 1];
        const unsigned bits = __float_as_uint(B.z);

        float4 f;
        {
            const int is = bits & 7, il = (bits >> 9) & 7;
            const float4 vs = *(const float4*)(slab + is * ROW_STRIDE + 4 * j);
            const float4 vl = *(const float4*)(slab + il * ROW_STRIDE + 4 * j);
            f.x = vs.x * A.x + vl.x * A.w;
            f.y = vs.y * A.x + vl.y * A.w;
            f.z = vs.z * A.x + vl.z * A.w;
            f.w = vs.w * A.x + vl.w * A.w;
        }
        {
            const int is = (bits >> 3) & 7, il = (bits >> 12) & 7;
            const float4 vs = *(const float4*)(slab + (8 + is) * ROW_STRIDE + 4 * j);
            const float4 vl = *(const float4*)(slab + (8 + il) * ROW_STRIDE + 4 * j);
            f.x *= vs.x * A.y + vl.x * B.x;
            f.y *= vs.y * A.y + vl.y * B.x;
            f.z *= vs.z * A.y + vl.z * B.x;
            f.w *= vs.w * A.y + vl.w * B.x;
        }
        {
            const int is = (bits >> 6) & 7, il = (bits >> 15) & 7;
            const float4 vs = *(const float4*)(slab + (16 + is) * ROW_STRIDE + 4 * j);
            const float4 vl = *(const float4*)(slab + (16 + il) * ROW_STRIDE + 4 * j);
            f.x *= vs.x * A.z + vl.x * B.y;
            f.y *= vs.y * A.z + vl.y * B.y;
            f.z *= vs.z * A.z + vl.z * B.y;
            f.w *= vs.w * A.z + vl.w * B.y;
        }

        float s0 = f.x * dens4.x + f.y * dens4.y + f.z * dens4.z + f.w * dens4.w;
        float s1 = f.x * col0.x  + f.y * col0.y  + f.z * col0.z  + f.w * col0.w;
        float s2 = f.x * col1.x  + f.y * col1.y  + f.z * col1.z  + f.w * col1.w;
        float s3 = f.x * col2.x  + f.y * col2.y  + f.z * col2.z  + f.w * col2.w;

        s0 += __shfl_xor(s0, 1); s0 += __shfl_xor(s0, 2);
        s1 += __shfl_xor(s1, 1); s1 += __shfl_xor(s1, 2);
        s2 += __shfl_xor(s2, 1); s2 += __shfl_xor(s2, 2);
        s3 += __shfl_xor(s3, 1); s3 += __shfl_xor(s3, 2);

        const float sj = (j == 0) ? s0 : (j == 1) ? s1 : (j == 2) ? s2 : s3;
        float val;
        if (j == 0) {
            float dens = fmaxf(sj, 0.0f) + __logf(1.0f + __expf(-fabsf(sj)));
            val = -(dens * DENS_SCALE) * STEP_SZ;            // lt
        } else {
            val = 1.0f / (1.0f + __expf(-sj));               // sigmoid
        }
        // coalesced: addresses (pos*4+j) are contiguous across the wave
        if (valid) results_f[(size_t)pos * 4 + j] = val;
    }
}

// ---------------------------------------------------------------------------
// Final pass: one thread per ray; results accessed via iperm (random 16B R).
// ---------------------------------------------------------------------------
__global__ __launch_bounds__(256) void ray_render(
    const float4* __restrict__ results,   // tid-order
    const int*    __restrict__ iperm,     // n -> pos
    const float*  __restrict__ t_min,
    const float*  __restrict__ bg,
    const int*    __restrict__ ray_start,
    const int*    __restrict__ step_id,
    float* __restrict__ out)
{
    int r = blockIdx.x * 256 + threadIdx.x;
    if (r >= N_RAYS) return;
    const int s = ray_start[r];
    const int e = ray_start[r + 1];
    const float tmin_r = t_min[r];

    float T = 0.0f, aR = 0.0f, aG = 0.0f, aB = 0.0f, aD = 0.0f;
    for (int n = s; n < e; ++n) {
        const int pos = iperm[n];
        float4 res = results[pos];
        const float lt = res.x;
        const float w = (1.0f - __expf(lt)) * __expf(T);
        T += lt;
        const float z = tmin_r + (float)step_id[n] * STEP_SZ;
        aR += w * res.y;
        aG += w * res.z;
        aB += w * res.w;
        aD += w * z;
    }
    const float bgw = __expf(T);
    out[0 * N_RAYS + r] = aR + bgw * bg[0];
    out[1 * N_RAYS + r] = aG + bgw * bg[1];
    out[2 * N_RAYS + r] = aB + bgw * bg[2];
    out[3 * N_RAYS + r] = aD;
    out[4 * N_RAYS + r] = 1.0f - bgw;
}

// ---------------------------------------------------------------------------
// Fallback (ws too small): single fused kernel, original layouts.
// ---------------------------------------------------------------------------
__global__ __launch_bounds__(256) void trivec_render_fallback(
    const float* __restrict__ trivecs, const float* __restrict__ densities,
    const float* __restrict__ colors, const float* __restrict__ gws,
    const float* __restrict__ gwl, const float* __restrict__ t_min,
    const float* __restrict__ bg, const int* __restrict__ gis,
    const int* __restrict__ gil, const int* __restrict__ tenso_id,
    const int* __restrict__ ray_id, const int* __restrict__ step_id,
    float* __restrict__ out)
{
    const int lane = threadIdx.x & 63;
    const int r = blockIdx.x * 4 + (threadIdx.x >> 6);
    if (r >= N_RAYS) return;
    const int c = lane & 15;
    const int g = lane >> 4;
    int lo = 0, hi = N_SAMP;
    while (lo < hi) { int mid = (lo + hi) >> 1; if (ray_id[mid] < r) lo = mid + 1; else hi = mid; }
    const int seg_start = lo;
    hi = N_SAMP;
    while (lo < hi) { int mid = (lo + hi) >> 1; if (ray_id[mid] < r + 1) lo = mid + 1; else hi = mid; }
    const int seg_end = lo;
    const float tmin_r = t_min[r];
    float Tlog = 0.0f, accR = 0.0f, accG = 0.0f, accB = 0.0f, accD = 0.0f;
    const int niter = (seg_end - seg_start + 3) >> 2;
    for (int it = 0; it < niter; ++it) {
        const int n = seg_start + it * 4 + g;
        const bool valid = (n < seg_end);
        const int nc = valid ? n : (seg_end - 1);
        const int tid = tenso_id[nc];
        const float* tv = trivecs + (size_t)tid * 384 + c * 24;
        float f = 1.0f;
        #pragma unroll
        for (int a = 0; a < 3; ++a) {
            const int is = gis[nc*3+a], il = gil[nc*3+a];
            const float wS = gws[nc*3+a], wL = gwl[nc*3+a];
            f *= (tv[a*8+is] * wS + tv[a*8+il] * wL);
        }
        const float dns = densities[(size_t)tid * 16 + c];
        const float* colp = colors + ((size_t)tid * 16 + c) * 3;
        float s0 = f*dns, s1 = f*colp[0], s2 = f*colp[1], s3 = f*colp[2];
        #pragma unroll
        for (int m = 1; m < 16; m <<= 1) {
            s0 += __shfl_xor(s0, m); s1 += __shfl_xor(s1, m);
            s2 += __shfl_xor(s2, m); s3 += __shfl_xor(s3, m);
        }
        float dens = fmaxf(s0, 0.0f) + __logf(1.0f + __expf(-fabsf(s0)));
        const float lt = valid ? (-dens * STEP_SZ) : 0.0f;
        const float alpha = 1.0f - __expf(lt);
        const float rr = 1.0f/(1.0f+__expf(-s1)), gg = 1.0f/(1.0f+__expf(-s2)), bb = 1.0f/(1.0f+__expf(-s3));
        const float z = tmin_r + (float)step_id[nc] * STEP_SZ;
        const float lt0 = __shfl(lt,0), lt1 = __shfl(lt,16), lt2 = __shfl(lt,32), lt3 = __shfl(lt,48);
        float excl = Tlog;
        if (g > 0) excl += lt0;
        if (g > 1) excl += lt1;
        if (g > 2) excl += lt2;
        const float w = alpha * __expf(excl);
        Tlog += lt0 + lt1 + lt2 + lt3;
        accR += w*rr; accG += w*gg; accB += w*bb; accD += w*z;
    }
    accR += __shfl_xor(accR,16); accR += __shfl_xor(accR,32);
    accG += __shfl_xor(accG,16); accG += __shfl_xor(accG,32);
    accB += __shfl_xor(accB,16); accB += __shfl_xor(accB,32);
    accD += __shfl_xor(accD,16); accD += __shfl_xor(accD,32);
    const float bgw = __expf(Tlog);
    if (lane == 0) {
        out[0*N_RAYS+r] = accR + bgw*bg[0];
        out[1*N_RAYS+r] = accG + bgw*bg[1];
        out[2*N_RAYS+r] = accB + bgw*bg[2];
        out[3*N_RAYS+r] = accD;
        out[4*N_RAYS+r] = 1.0f - bgw;
    }
}

extern "C" void kernel_launch(void* const* d_in, const int* in_sizes, int n_in,
                              void* d_out, int out_size, void* d_ws, size_t ws_size,
                              hipStream_t stream) {
    const float* trivecs   = (const float*)d_in[0];
    const float* densities = (const float*)d_in[1];
    const float* colors    = (const float*)d_in[2];
    const float* gws       = (const float*)d_in[3];
    const float* gwl       = (const float*)d_in[4];
    const float* t_min     = (const float*)d_in[5];
    const float* bg        = (const float*)d_in[6];
    const int*   gis       = (const int*)d_in[7];
    const int*   gil       = (const int*)d_in[8];
    const int*   tenso_id  = (const int*)d_in[9];
    const int*   ray_id    = (const int*)d_in[10];
    const int*   step_id   = (const int*)d_in[11];
    float* out = (float*)d_out;

    if (ws_size < (size_t)WS_NEED) {
        trivec_render_fallback<<<(N_RAYS + 3) / 4, 256, 0, stream>>>(
            trivecs, densities, colors, gws, gwl, t_min, bg,
            gis, gil, tenso_id, ray_id, step_id, out);
        return;
    }

    char* ws = (char*)d_ws;
    float4* pack     = (float4*)(ws + OFF_PACK);
    float4* results  = (float4*)(ws + OFF_RESULTS);
    int*    perm     = (int*)(ws + OFF_PERM);
    int*    iperm    = (int*)(ws + OFF_IPERM);
    int*    counts   = (int*)(ws + OFF_COUNTS);
    int*    starts   = (int*)(ws + OFF_STARTS);
    int*    cursor   = (int*)(ws + OFF_CURSOR);
    int*    bsums    = (int*)(ws + OFF_BSUMS);
    int*    raystart = (int*)(ws + OFF_RSTART);

    zero_ints<<<(P_TENSO + 255) / 256, 256, 0, stream>>>(counts, P_TENSO);
    pack_hist_bounds<<<(N_SAMP + 255) / 256, 256, 0, stream>>>(
        tenso_id, ray_id, gis, gil, gws, gwl, counts, raystart, pack);
    scan_local<<<NB_SCAN, 256, 0, stream>>>(counts, starts, bsums, P_TENSO);
    scan_totals<<<1, 64, 0, stream>>>(bsums, NB_SCAN);
    scan_add<<<(P_TENSO + 255) / 256, 256, 0, stream>>>(starts, cursor, bsums, P_TENSO);
    scatter_perm<<<(N_SAMP + 255) / 256, 256, 0, stream>>>(tenso_id, cursor, perm, iperm);
    gather_phase<<<(P_TENSO + 3) / 4, 256, 0, stream>>>(
        trivecs, densities, colors, starts, counts, perm, pack, (float*)results);
    ray_render<<<(N_RAYS + 255) / 256, 256, 0, stream>>>(
        results, iperm, t_min, bg, raystart, step_id, out);
}

// Round 9
// 284.730 us; speedup vs baseline: 2.9203x; 1.1799x over previous
//
#include <hip/hip_runtime.h>
#include <math.h>

#define HN       250
#define WN       400
#define N_RAYS   (HN * WN)        // 100000
#define N_SAMP   1000000
#define P_TENSO  50000
#define STEP_SZ  0.005f
#define DENS_SCALE 1.0f           // min(1/(1-0), 25) = 1
#define NB_SCAN  ((P_TENSO + 1023) / 1024)   // 49

// NOTE (R7): cooperative grid.sync() measured ~100 us/sync on MI355X — do not
// re-fuse with cooperative launch. NOTE (R8): each device-scope returning
// atomicAdd costs a 64B line transaction (1M atomics == 64 MB WRITE_SIZE);
// the atomic pass, not the payload writes, dominates scatter-type kernels.

// ---------------- workspace layout (bytes) ----------------
#define OFF_PACK    0            // 1M x 32B sample structs, original order
#define OFF_RESULTS 32000000     // 1M x 16B (lt,r,g,b), tid order
#define OFF_PERM    48000000     // 1M int, pos -> n
#define OFF_IPERM   52000000     // 1M int, n -> pos
#define OFF_RANK    56000000     // 1M int, rank within tid
#define OFF_CURSOR  60000000     // 50K int (atomic counters == final counts)
#define OFF_STARTS  60200000     // 50K int
#define OFF_BSUMS   60400000     // 64 int
#define OFF_FLAG    60400512     // 1 int (spin-barrier arrival)
#define OFF_RSTART  60401024     // (N_RAYS+1) int
#define WS_NEED     (60401024 + 400004 + 64)

// gather slab layout (floats), per wave
#define ROW_STRIDE 20                 // 16 ch + 4 pad
#define TV_F   (24 * ROW_STRIDE)      // 480
#define SLAB_F (TV_F + 16 + 48)       // 544

// ---------------------------------------------------------------------------
// A: pack (coalesced 32B W) + ray bounds + rank via ONE returning atomic pass
// ---------------------------------------------------------------------------
__global__ __launch_bounds__(256) void pack_bounds_rank(
    const int*   __restrict__ tenso_id,
    const int*   __restrict__ ray_id,     // sorted
    const int*   __restrict__ gis, const int* __restrict__ gil,
    const float* __restrict__ gws, const float* __restrict__ gwl,
    int* __restrict__ cursor,             // zeroed; becomes counts
    int* __restrict__ rank,
    int* __restrict__ ray_start,
    float4* __restrict__ pack)
{
    int n = blockIdx.x * 256 + threadIdx.x;
    if (n >= N_SAMP) return;

    const int tid = tenso_id[n];
    rank[n] = atomicAdd(&cursor[tid], 1);          // the single atomic pass

    unsigned bits = (unsigned)gis[n*3+0] | ((unsigned)gis[n*3+1] << 3) | ((unsigned)gis[n*3+2] << 6)
                  | ((unsigned)gil[n*3+0] << 9) | ((unsigned)gil[n*3+1] << 12) | ((unsigned)gil[n*3+2] << 15);
    float4 A = make_float4(gws[n*3+0], gws[n*3+1], gws[n*3+2], gwl[n*3+0]);
    float4 B = make_float4(gwl[n*3+1], gwl[n*3+2], __uint_as_float(bits), 0.0f);
    pack[(size_t)n * 2 + 0] = A;
    pack[(size_t)n * 2 + 1] = B;

    int r = ray_id[n];
    int rprev = (n == 0) ? -1 : ray_id[n - 1];
    for (int q = rprev + 1; q <= r; ++q) ray_start[q] = n;
    if (n == N_SAMP - 1) {
        for (int q = r + 1; q <= N_RAYS; ++q) ray_start[q] = N_SAMP;
    }
}

// ---------------------------------------------------------------------------
// B: fused exclusive scan of counts -> starts. 49 blocks (co-resident on 256
// CUs), internal spin barrier on an arrival counter.
// ---------------------------------------------------------------------------
__global__ __launch_bounds__(256) void scan_fused(
    const int* __restrict__ cursor,   // counts
    int* __restrict__ starts,
    int* __restrict__ bsums,
    int* __restrict__ flag)
{
    __shared__ int lds[257];
    const int b = blockIdx.x;
    const int t = threadIdx.x;
    const int base = b * 1024 + t * 4;

    int v[4]; int s = 0;
    #pragma unroll
    for (int i = 0; i < 4; ++i) {
        int idx = base + i;
        v[i] = (idx < P_TENSO) ? cursor[idx] : 0;
        s += v[i];
    }
    lds[t] = s;
    __syncthreads();
    for (int d = 1; d < 256; d <<= 1) {
        int x = (t >= d) ? lds[t - d] : 0;
        __syncthreads();
        lds[t] += x;
        __syncthreads();
    }
    if (t == 255) bsums[b] = lds[255];

    // ---- barrier across the 49 blocks ----
    __threadfence();
    __syncthreads();
    if (t == 0) {
        atomicAdd(flag, 1);
        while (atomicAdd(flag, 0) < gridDim.x) { }
    }
    __syncthreads();
    __threadfence();

    // every block computes its global prefix = sum of bsums[0..b)
    if (t < 64) {
        int x = (t < b) ? bsums[t] : 0;
        #pragma unroll
        for (int m = 1; m < 64; m <<= 1) x += __shfl_xor(x, m);
        if (t == 0) lds[256] = x;
    }
    __syncthreads();
    const int pre = lds[256];

    int run = pre + ((t > 0) ? lds[t - 1] : 0);
    #pragma unroll
    for (int i = 0; i < 4; ++i) {
        int idx = base + i;
        if (idx < P_TENSO) starts[idx] = run;
        run += v[i];
    }
}

// ---------------------------------------------------------------------------
// C: positions without atomics: pos = starts[tid] + rank[n]
// ---------------------------------------------------------------------------
__global__ __launch_bounds__(256) void finalize_perm(
    const int* __restrict__ tenso_id,
    const int* __restrict__ rank,
    const int* __restrict__ starts,
    int* __restrict__ perm,
    int* __restrict__ iperm)
{
    int n = blockIdx.x * 256 + threadIdx.x;
    if (n >= N_SAMP) return;
    int pos = starts[tenso_id[n]] + rank[n];
    iperm[n] = pos;          // coalesced
    perm[pos] = n;           // random 4B into 4MB (L2-resident)
}

// ---------------------------------------------------------------------------
// Gather: one wave per tensoRF id; lanes = 16 samples x 4 channel-groups.
// ---------------------------------------------------------------------------
__global__ __launch_bounds__(256) void gather_phase(
    const float* __restrict__ trivecs,   // (P,16,3,8)
    const float* __restrict__ densities, // (P,16)
    const float* __restrict__ colors,    // (P,16,3)
    const int*   __restrict__ starts,
    const int*   __restrict__ counts,    // == cursor
    const int*   __restrict__ perm,
    const float4* __restrict__ pack,
    float* __restrict__ results_f)       // [pos*4 + j]
{
    __shared__ __align__(16) float lds[4 * SLAB_F];
    const int lane = threadIdx.x & 63;
    const int wv   = threadIdx.x >> 6;
    const int t    = blockIdx.x * 4 + wv;
    if (t >= P_TENSO) return;

    const int start = starts[t];
    const int cnt   = counts[t];
    if (cnt == 0) return;

    float* slab = lds + wv * SLAB_F;
    float* dl   = slab + TV_F;
    float* cl   = dl + 16;

    const float* tvg = trivecs + (size_t)t * 384;
    #pragma unroll
    for (int i = 0; i < 6; ++i) {
        int l = lane + i * 64;
        int c = l / 24;
        int rem = l - c * 24;
        slab[rem * ROW_STRIDE + c] = tvg[l];
    }
    if (lane < 16) dl[lane] = densities[(size_t)t * 16 + lane];
    if (lane < 48) {
        int c = lane / 3, k = lane - c * 3;
        cl[k * 16 + c] = colors[(size_t)t * 48 + lane];
    }

    const int g = lane >> 2;   // sample slot 0..15
    const int j = lane & 3;    // channel group

    const float4 dens4 = *(const float4*)(dl + 4 * j);
    const float4 col0  = *(const float4*)(cl + 4 * j);
    const float4 col1  = *(const float4*)(cl + 16 + 4 * j);
    const float4 col2  = *(const float4*)(cl + 32 + 4 * j);

    const int end = start + cnt;
    const int niter = (cnt + 15) >> 4;

    for (int it = 0; it < niter; ++it) {
        const int pos = start + it * 16 + g;
        const bool valid = (pos < end);
        const int cp = valid ? pos : (end - 1);
        const int n = perm[cp];                       // coalesced
        const float4 A = pack[(size_t)n * 2 + 0];     // random 32B, quad-broadcast
        const float4 B = pack[(size_t)n * 2 + 1];
        const unsigned bits = __float_as_uint(B.z);

        float4 f;
        {
            const int is = bits & 7, il = (bits >> 9) & 7;
            const float4 vs = *(const float4*)(slab + is * ROW_STRIDE + 4 * j);
            const float4 vl = *(const float4*)(slab + il * ROW_STRIDE + 4 * j);
            f.x = vs.x * A.x + vl.x * A.w;
            f.y = vs.y * A.x + vl.y * A.w;
            f.z = vs.z * A.x + vl.z * A.w;
            f.w = vs.w * A.x + vl.w * A.w;
        }
        {
            const int is = (bits >> 3) & 7, il = (bits >> 12) & 7;
            const float4 vs = *(const float4*)(slab + (8 + is) * ROW_STRIDE + 4 * j);
            const float4 vl = *(const float4*)(slab + (8 + il) * ROW_STRIDE + 4 * j);
            f.x *= vs.x * A.y + vl.x * B.x;
            f.y *= vs.y * A.y + vl.y * B.x;
            f.z *= vs.z * A.y + vl.z * B.x;
            f.w *= vs.w * A.y + vl.w * B.x;
        }
        {
            const int is = (bits >> 6) & 7, il = (bits >> 15) & 7;
            const float4 vs = *(const float4*)(slab + (16 + is) * ROW_STRIDE + 4 * j);
            const float4 vl = *(const float4*)(slab + (16 + il) * ROW_STRIDE + 4 * j);
            f.x *= vs.x * A.z + vl.x * B.y;
            f.y *= vs.y * A.z + vl.y * B.y;
            f.z *= vs.z * A.z + vl.z * B.y;
            f.w *= vs.w * A.z + vl.w * B.y;
        }

        float s0 = f.x * dens4.x + f.y * dens4.y + f.z * dens4.z + f.w * dens4.w;
        float s1 = f.x * col0.x  + f.y * col0.y  + f.z * col0.z  + f.w * col0.w;
        float s2 = f.x * col1.x  + f.y * col1.y  + f.z * col1.z  + f.w * col1.w;
        float s3 = f.x * col2.x  + f.y * col2.y  + f.z * col2.z  + f.w * col2.w;

        s0 += __shfl_xor(s0, 1); s0 += __shfl_xor(s0, 2);
        s1 += __shfl_xor(s1, 1); s1 += __shfl_xor(s1, 2);
        s2 += __shfl_xor(s2, 1); s2 += __shfl_xor(s2, 2);
        s3 += __shfl_xor(s3, 1); s3 += __shfl_xor(s3, 2);

        const float sj = (j == 0) ? s0 : (j == 1) ? s1 : (j == 2) ? s2 : s3;
        float val;
        if (j == 0) {
            float dens = fmaxf(sj, 0.0f) + __logf(1.0f + __expf(-fabsf(sj)));
            val = -(dens * DENS_SCALE) * STEP_SZ;            // lt
        } else {
            val = 1.0f / (1.0f + __expf(-sj));               // sigmoid
        }
        if (valid) results_f[(size_t)pos * 4 + j] = val;     // coalesced
    }
}

// ---------------------------------------------------------------------------
// E: one thread per ray; sequential recurrence; results via iperm.
// ---------------------------------------------------------------------------
__global__ __launch_bounds__(256) void ray_render(
    const float4* __restrict__ results,
    const int*    __restrict__ iperm,
    const float*  __restrict__ t_min,
    const float*  __restrict__ bg,
    const int*    __restrict__ ray_start,
    const int*    __restrict__ step_id,
    float* __restrict__ out)
{
    int r = blockIdx.x * 256 + threadIdx.x;
    if (r >= N_RAYS) return;
    const int s = ray_start[r];
    const int e = ray_start[r + 1];
    const float tmin_r = t_min[r];

    float T = 0.0f, aR = 0.0f, aG = 0.0f, aB = 0.0f, aD = 0.0f;
    for (int n = s; n < e; ++n) {
        const int pos = iperm[n];
        float4 res = results[pos];
        const float lt = res.x;
        const float w = (1.0f - __expf(lt)) * __expf(T);
        T += lt;
        const float z = tmin_r + (float)step_id[n] * STEP_SZ;
        aR += w * res.y;
        aG += w * res.z;
        aB += w * res.w;
        aD += w * z;
    }
    const float bgw = __expf(T);
    out[0 * N_RAYS + r] = aR + bgw * bg[0];
    out[1 * N_RAYS + r] = aG + bgw * bg[1];
    out[2 * N_RAYS + r] = aB + bgw * bg[2];
    out[3 * N_RAYS + r] = aD;
    out[4 * N_RAYS + r] = 1.0f - bgw;
}

// ---------------------------------------------------------------------------
// Fallback (ws too small): single fused kernel, original layouts.
// ---------------------------------------------------------------------------
__global__ __launch_bounds__(256) void trivec_render_fallback(
    const float* __restrict__ trivecs, const float* __restrict__ densities,
    const float* __restrict__ colors, const float* __restrict__ gws,
    const float* __restrict__ gwl, const float* __restrict__ t_min,
    const float* __restrict__ bg, const int* __restrict__ gis,
    const int* __restrict__ gil, const int* __restrict__ tenso_id,
    const int* __restrict__ ray_id, const int* __restrict__ step_id,
    float* __restrict__ out)
{
    const int lane = threadIdx.x & 63;
    const int r = blockIdx.x * 4 + (threadIdx.x >> 6);
    if (r >= N_RAYS) return;
    const int c = lane & 15;
    const int g = lane >> 4;
    int lo = 0, hi = N_SAMP;
    while (lo < hi) { int mid = (lo + hi) >> 1; if (ray_id[mid] < r) lo = mid + 1; else hi = mid; }
    const int seg_start = lo;
    hi = N_SAMP;
    while (lo < hi) { int mid = (lo + hi) >> 1; if (ray_id[mid] < r + 1) lo = mid + 1; else hi = mid; }
    const int seg_end = lo;
    const float tmin_r = t_min[r];
    float Tlog = 0.0f, accR = 0.0f, accG = 0.0f, accB = 0.0f, accD = 0.0f;
    const int niter = (seg_end - seg_start + 3) >> 2;
    for (int it = 0; it < niter; ++it) {
        const int n = seg_start + it * 4 + g;
        const bool valid = (n < seg_end);
        const int nc = valid ? n : (seg_end - 1);
        const int tid = tenso_id[nc];
        const float* tv = trivecs + (size_t)tid * 384 + c * 24;
        float f = 1.0f;
        #pragma unroll
        for (int a = 0; a < 3; ++a) {
            const int is = gis[nc*3+a], il = gil[nc*3+a];
            const float wS = gws[nc*3+a], wL = gwl[nc*3+a];
            f *= (tv[a*8+is] * wS + tv[a*8+il] * wL);
        }
        const float dns = densities[(size_t)tid * 16 + c];
        const float* colp = colors + ((size_t)tid * 16 + c) * 3;
        float s0 = f*dns, s1 = f*colp[0], s2 = f*colp[1], s3 = f*colp[2];
        #pragma unroll
        for (int m = 1; m < 16; m <<= 1) {
            s0 += __shfl_xor(s0, m); s1 += __shfl_xor(s1, m);
            s2 += __shfl_xor(s2, m); s3 += __shfl_xor(s3, m);
        }
        float dens = fmaxf(s0, 0.0f) + __logf(1.0f + __expf(-fabsf(s0)));
        const float lt = valid ? (-dens * STEP_SZ) : 0.0f;
        const float alpha = 1.0f - __expf(lt);
        const float rr = 1.0f/(1.0f+__expf(-s1)), gg = 1.0f/(1.0f+__expf(-s2)), bb = 1.0f/(1.0f+__expf(-s3));
        const float z = tmin_r + (float)step_id[nc] * STEP_SZ;
        const float lt0 = __shfl(lt,0), lt1 = __shfl(lt,16), lt2 = __shfl(lt,32), lt3 = __shfl(lt,48);
        float excl = Tlog;
        if (g > 0) excl += lt0;
        if (g > 1) excl += lt1;
        if (g > 2) excl += lt2;
        const float w = alpha * __expf(excl);
        Tlog += lt0 + lt1 + lt2 + lt3;
        accR += w*rr; accG += w*gg; accB += w*bb; accD += w*z;
    }
    accR += __shfl_xor(accR,16); accR += __shfl_xor(accR,32);
    accG += __shfl_xor(accG,16); accG += __shfl_xor(accG,32);
    accB += __shfl_xor(accB,16); accB += __shfl_xor(accB,32);
    accD += __shfl_xor(accD,16); accD += __shfl_xor(accD,32);
    const float bgw = __expf(Tlog);
    if (lane == 0) {
        out[0*N_RAYS+r] = accR + bgw*bg[0];
        out[1*N_RAYS+r] = accG + bgw*bg[1];
        out[2*N_RAYS+r] = accB + bgw*bg[2];
        out[3*N_RAYS+r] = accD;
        out[4*N_RAYS+r] = 1.0f - bgw;
    }
}

extern "C" void kernel_launch(void* const* d_in, const int* in_sizes, int n_in,
                              void* d_out, int out_size, void* d_ws, size_t ws_size,
                              hipStream_t stream) {
    const float* trivecs   = (const float*)d_in[0];
    const float* densities = (const float*)d_in[1];
    const float* colors    = (const float*)d_in[2];
    const float* gws       = (const float*)d_in[3];
    const float* gwl       = (const float*)d_in[4];
    const float* t_min     = (const float*)d_in[5];
    const float* bg        = (const float*)d_in[6];
    const int*   gis       = (const int*)d_in[7];
    const int*   gil       = (const int*)d_in[8];
    const int*   tenso_id  = (const int*)d_in[9];
    const int*   ray_id    = (const int*)d_in[10];
    const int*   step_id   = (const int*)d_in[11];
    float* out = (float*)d_out;

    if (ws_size < (size_t)WS_NEED) {
        trivec_render_fallback<<<(N_RAYS + 3) / 4, 256, 0, stream>>>(
            trivecs, densities, colors, gws, gwl, t_min, bg,
            gis, gil, tenso_id, ray_id, step_id, out);
        return;
    }

    char* ws = (char*)d_ws;
    float4* pack     = (float4*)(ws + OFF_PACK);
    float4* results  = (float4*)(ws + OFF_RESULTS);
    int*    perm     = (int*)(ws + OFF_PERM);
    int*    iperm    = (int*)(ws + OFF_IPERM);
    int*    rank     = (int*)(ws + OFF_RANK);
    int*    cursor   = (int*)(ws + OFF_CURSOR);
    int*    starts   = (int*)(ws + OFF_STARTS);
    int*    bsums    = (int*)(ws + OFF_BSUMS);
    int*    flag     = (int*)(ws + OFF_FLAG);
    int*    raystart = (int*)(ws + OFF_RSTART);

    // zero cursor + bsums + flag in one async memset (covers 60.0e6..60401088)
    hipMemsetAsync(ws + OFF_CURSOR, 0, (OFF_FLAG + 64) - OFF_CURSOR, stream);

    pack_bounds_rank<<<(N_SAMP + 255) / 256, 256, 0, stream>>>(
        tenso_id, ray_id, gis, gil, gws, gwl, cursor, rank, raystart, pack);
    scan_fused<<<NB_SCAN, 256, 0, stream>>>(cursor, starts, bsums, flag);
    finalize_perm<<<(N_SAMP + 255) / 256, 256, 0, stream>>>(
        tenso_id, rank, starts, perm, iperm);
    gather_phase<<<(P_TENSO + 3) / 4, 256, 0, stream>>>(
        trivecs, densities, colors, starts, cursor, perm, pack, (float*)results);
    ray_render<<<(N_RAYS + 255) / 256, 256, 0, stream>>>(
        results, iperm, t_min, bg, raystart, step_id, out);
}